// Round 1
// 54.220 us; speedup vs baseline: 1.5128x; 1.5128x over previous
//
#include <hip/hip_runtime.h>
#include <hip/hip_fp16.h>

#define SIGMA_F   1e-4f
#define GAMMA_F   1e-4f
#define ZNEAR_F   1.0f
#define ZFAR_F    100.0f
#define EPS_F     1e-10f

// ---------------------------------------------------------------------------
// Kernel A: materialize per-face vertex normals as f16, padded to 32 B/face.
// attrs[f] = { n0x n0y n0z n1x n1y n1z n2x n2y n2z, 7 x pad } (16 halves)
// ---------------------------------------------------------------------------
struct __align__(16) H16 { __half h[16]; };

__global__ __launch_bounds__(256) void build_face_attrs(
    const int*   __restrict__ faces,
    const float* __restrict__ vnorm,
    H16*         __restrict__ attrs,
    int F)
{
    int f = blockIdx.x * blockDim.x + threadIdx.x;
    if (f >= F) return;
    int v0 = faces[(size_t)f * 3 + 0];
    int v1 = faces[(size_t)f * 3 + 1];
    int v2 = faces[(size_t)f * 3 + 2];

    H16 a;
    a.h[0] = __float2half(vnorm[(size_t)v0 * 3 + 0]);
    a.h[1] = __float2half(vnorm[(size_t)v0 * 3 + 1]);
    a.h[2] = __float2half(vnorm[(size_t)v0 * 3 + 2]);
    a.h[3] = __float2half(vnorm[(size_t)v1 * 3 + 0]);
    a.h[4] = __float2half(vnorm[(size_t)v1 * 3 + 1]);
    a.h[5] = __float2half(vnorm[(size_t)v1 * 3 + 2]);
    a.h[6] = __float2half(vnorm[(size_t)v2 * 3 + 0]);
    a.h[7] = __float2half(vnorm[(size_t)v2 * 3 + 1]);
    a.h[8] = __float2half(vnorm[(size_t)v2 * 3 + 2]);
    #pragma unroll
    for (int i = 9; i < 16; ++i) a.h[i] = __half(0.0f);
    attrs[f] = a;
}

// ---------------------------------------------------------------------------
// Kernel B: one thread per pixel.
// Depth-cull: with GAMMA=1e-4, w_k = prob_k * exp((zinv_k - zmax)*1e4)
// underflows to exactly 0 once a face trails the closest by >0.87 depth units.
// Compute all weights from streaming data (p2f/dists/zbuf) FIRST, then gather
// normals + load bary ONLY for slots with arg > -60 (w > ~9e-27, i.e. slots
// that contribute anything representable vs denom >= prob_kmax).
// Typically ~1 of 8 slots survives -> ~8x fewer divergent gather transactions.
// ---------------------------------------------------------------------------
__global__ __launch_bounds__(256) void shade_kernel(
    const int*   __restrict__ pix_to_face,
    const float* __restrict__ bary,
    const float* __restrict__ dists,
    const float* __restrict__ zbuf,
    const H16*   __restrict__ attrs,
    float*       __restrict__ out,
    int P)
{
    int pix = blockIdx.x * blockDim.x + threadIdx.x;
    if (pix >= P) return;

    const int4* p2f4 = reinterpret_cast<const int4*>(pix_to_face + (size_t)pix * 8);
    int4 f0 = p2f4[0], f1 = p2f4[1];
    int faceid[8] = {f0.x, f0.y, f0.z, f0.w, f1.x, f1.y, f1.z, f1.w};

    const float4* d4 = reinterpret_cast<const float4*>(dists + (size_t)pix * 8);
    float4 da = d4[0], db = d4[1];
    float dd[8] = {da.x, da.y, da.z, da.w, db.x, db.y, db.z, db.w};

    const float4* z4 = reinterpret_cast<const float4*>(zbuf + (size_t)pix * 8);
    float4 za = z4[0], zb = z4[1];
    float zz[8] = {za.x, za.y, za.z, za.w, zb.x, zb.y, zb.z, zb.w};

    const float inv_sigma = 1.0f / SIGMA_F;
    const float inv_range = 1.0f / (ZFAR_F - ZNEAR_F);

    // Pass 1: weights-only quantities (no gather needed).
    float prob[8], zinv[8];
    float zmax = EPS_F;
    float one_minus_prod = 1.0f;

    #pragma unroll
    for (int k = 0; k < 8; ++k) {
        bool m = faceid[k] >= 0;
        float pm = m ? 1.0f / (1.0f + __expf(dd[k] * inv_sigma)) : 0.0f;
        prob[k] = pm;
        one_minus_prod *= (1.0f - pm);
        float zi = m ? (ZFAR_F - zz[k]) * inv_range : 0.0f;
        zinv[k] = zi;
        zmax = fmaxf(zmax, zi);
    }

    float alpha = 1.0f - one_minus_prod;

    // Pass 2: wsum over ALL slots (exact); gather + bary only where the
    // weight is non-negligible.
    const float inv_gamma = 1.0f / GAMMA_F;
    const float* bp = bary + (size_t)pix * 24;

    float wsum = 0.0f, cr = 0.0f, cg = 0.0f, cb = 0.0f;
    #pragma unroll
    for (int k = 0; k < 8; ++k) {
        float arg = (zinv[k] - zmax) * inv_gamma;          // <= 0
        float w = prob[k] * __expf(arg);                   // exact underflow -> 0
        wsum += w;
        if (prob[k] > 0.0f && arg > -60.0f) {
            float b0 = bp[k * 3 + 0];
            float b1 = bp[k * 3 + 1];
            float b2 = bp[k * 3 + 2];
            H16 g = attrs[faceid[k]];
            float px = b0 * __half2float(g.h[0]) + b1 * __half2float(g.h[3]) + b2 * __half2float(g.h[6]);
            float py = b0 * __half2float(g.h[1]) + b1 * __half2float(g.h[4]) + b2 * __half2float(g.h[7]);
            float pz = b0 * __half2float(g.h[2]) + b1 * __half2float(g.h[5]) + b2 * __half2float(g.h[8]);
            cr += w * px;
            cg += w * py;
            cb += w * pz;
        }
    }

    float delta = fmaxf(__expf((EPS_F - zmax) * inv_gamma), EPS_F);
    float inv_denom = 1.0f / (wsum + delta);

    float4 o;
    o.x = (cr + delta) * inv_denom;   // BG_COLOR = (1,1,1)
    o.y = (cg + delta) * inv_denom;
    o.z = (cb + delta) * inv_denom;
    o.w = alpha;
    reinterpret_cast<float4*>(out)[pix] = o;
}

// ---------------------------------------------------------------------------
// Fallback (fused double-indirection) if ws_size is too small for attr table.
// ---------------------------------------------------------------------------
__global__ __launch_bounds__(256) void normal_shader_fused(
    const int*   __restrict__ pix_to_face,
    const float* __restrict__ bary,
    const float* __restrict__ dists,
    const float* __restrict__ zbuf,
    const int*   __restrict__ faces,
    const float* __restrict__ vnorm,
    float*       __restrict__ out,
    int P)
{
    int pix = blockIdx.x * blockDim.x + threadIdx.x;
    if (pix >= P) return;

    const int4* p2f4 = reinterpret_cast<const int4*>(pix_to_face + (size_t)pix * 8);
    int4 f0 = p2f4[0], f1 = p2f4[1];
    int faceid[8] = {f0.x, f0.y, f0.z, f0.w, f1.x, f1.y, f1.z, f1.w};

    const float4* d4 = reinterpret_cast<const float4*>(dists + (size_t)pix * 8);
    float4 da = d4[0], db = d4[1];
    float dd[8] = {da.x, da.y, da.z, da.w, db.x, db.y, db.z, db.w};

    const float4* z4 = reinterpret_cast<const float4*>(zbuf + (size_t)pix * 8);
    float4 za = z4[0], zb = z4[1];
    float zz[8] = {za.x, za.y, za.z, za.w, zb.x, zb.y, zb.z, zb.w};

    const float inv_sigma = 1.0f / SIGMA_F;
    const float inv_range = 1.0f / (ZFAR_F - ZNEAR_F);

    float prob[8], zinv[8];
    float zmax = EPS_F, one_minus_prod = 1.0f;

    #pragma unroll
    for (int k = 0; k < 8; ++k) {
        bool m = faceid[k] >= 0;
        float pm = m ? 1.0f / (1.0f + __expf(dd[k] * inv_sigma)) : 0.0f;
        prob[k] = pm;
        one_minus_prod *= (1.0f - pm);
        float zi = m ? (ZFAR_F - zz[k]) * inv_range : 0.0f;
        zinv[k] = zi;
        zmax = fmaxf(zmax, zi);
    }

    float alpha = 1.0f - one_minus_prod;

    const float inv_gamma = 1.0f / GAMMA_F;
    const float* bp = bary + (size_t)pix * 24;

    float wsum = 0.0f, cr = 0.0f, cg = 0.0f, cb = 0.0f;
    #pragma unroll
    for (int k = 0; k < 8; ++k) {
        float arg = (zinv[k] - zmax) * inv_gamma;
        float w = prob[k] * __expf(arg);
        wsum += w;
        if (prob[k] > 0.0f && arg > -60.0f) {
            int fi = faceid[k];
            int v0 = faces[(size_t)fi * 3 + 0];
            int v1 = faces[(size_t)fi * 3 + 1];
            int v2 = faces[(size_t)fi * 3 + 2];
            float b0 = bp[k * 3 + 0];
            float b1 = bp[k * 3 + 1];
            float b2 = bp[k * 3 + 2];
            const float* n0 = vnorm + (size_t)v0 * 3;
            const float* n1 = vnorm + (size_t)v1 * 3;
            const float* n2 = vnorm + (size_t)v2 * 3;
            float px = b0 * n0[0] + b1 * n1[0] + b2 * n2[0];
            float py = b0 * n0[1] + b1 * n1[1] + b2 * n2[1];
            float pz = b0 * n0[2] + b1 * n1[2] + b2 * n2[2];
            cr += w * px;
            cg += w * py;
            cb += w * pz;
        }
    }

    float delta = fmaxf(__expf((EPS_F - zmax) * inv_gamma), EPS_F);
    float inv_denom = 1.0f / (wsum + delta);
    float4 o;
    o.x = (cr + delta) * inv_denom;
    o.y = (cg + delta) * inv_denom;
    o.z = (cb + delta) * inv_denom;
    o.w = alpha;
    reinterpret_cast<float4*>(out)[pix] = o;
}

extern "C" void kernel_launch(void* const* d_in, const int* in_sizes, int n_in,
                              void* d_out, int out_size, void* d_ws, size_t ws_size,
                              hipStream_t stream) {
    const int*   pix_to_face = (const int*)  d_in[0];
    const float* bary        = (const float*)d_in[1];
    const float* dists       = (const float*)d_in[2];
    const float* zbuf        = (const float*)d_in[3];
    const int*   faces       = (const int*)  d_in[4];
    const float* vnorm       = (const float*)d_in[5];
    float*       out         = (float*)d_out;

    int P = out_size / 4;       // N*H*W pixels
    int F = in_sizes[4] / 3;    // number of faces
    int block = 256;
    int gridP = (P + block - 1) / block;

    size_t attrs_bytes = (size_t)F * sizeof(H16);
    if (ws_size >= attrs_bytes) {
        H16* attrs = (H16*)d_ws;
        int gridF = (F + block - 1) / block;
        build_face_attrs<<<gridF, block, 0, stream>>>(faces, vnorm, attrs, F);
        shade_kernel<<<gridP, block, 0, stream>>>(
            pix_to_face, bary, dists, zbuf, attrs, out, P);
    } else {
        normal_shader_fused<<<gridP, block, 0, stream>>>(
            pix_to_face, bary, dists, zbuf, faces, vnorm, out, P);
    }
}

// Round 3
// 52.760 us; speedup vs baseline: 1.5546x; 1.0277x over previous
//
#include <hip/hip_runtime.h>
#include <hip/hip_fp16.h>

#define SIGMA_F   1e-4f
#define GAMMA_F   1e-4f
#define ZNEAR_F   1.0f
#define ZFAR_F    100.0f
#define EPS_F     1e-10f

// Cull threshold: w = prob * exp((zinv - zmax)/GAMMA). exp(-60) ~ 8.8e-27,
// and denom >= delta >= 1e-10, so dropped terms are invisible at f32.
#define CULL_ARG  (-60.0f)

// Clang vector types: __builtin_nontemporal_load/store require real vector
// types, not HIP_vector_type structs (round-2 compile failure).
typedef float f32x4 __attribute__((ext_vector_type(4)));
typedef int   i32x4 __attribute__((ext_vector_type(4)));

// ---------------------------------------------------------------------------
// Kernel A: materialize per-face vertex normals as f16, padded to 32 B/face.
// attrs[f] = { n0x n0y n0z n1x n1y n1z n2x n2y n2z, 7 x pad } (16 halves)
// ---------------------------------------------------------------------------
struct __align__(16) H16 { __half h[16]; };

__global__ __launch_bounds__(256) void build_face_attrs(
    const int*   __restrict__ faces,
    const float* __restrict__ vnorm,
    H16*         __restrict__ attrs,
    int F)
{
    int f = blockIdx.x * blockDim.x + threadIdx.x;
    if (f >= F) return;
    int v0 = faces[(size_t)f * 3 + 0];
    int v1 = faces[(size_t)f * 3 + 1];
    int v2 = faces[(size_t)f * 3 + 2];

    H16 a;
    a.h[0] = __float2half(vnorm[(size_t)v0 * 3 + 0]);
    a.h[1] = __float2half(vnorm[(size_t)v0 * 3 + 1]);
    a.h[2] = __float2half(vnorm[(size_t)v0 * 3 + 2]);
    a.h[3] = __float2half(vnorm[(size_t)v1 * 3 + 0]);
    a.h[4] = __float2half(vnorm[(size_t)v1 * 3 + 1]);
    a.h[5] = __float2half(vnorm[(size_t)v1 * 3 + 2]);
    a.h[6] = __float2half(vnorm[(size_t)v2 * 3 + 0]);
    a.h[7] = __float2half(vnorm[(size_t)v2 * 3 + 1]);
    a.h[8] = __float2half(vnorm[(size_t)v2 * 3 + 2]);
    #pragma unroll
    for (int i = 9; i < 16; ++i) a.h[i] = __half(0.0f);
    attrs[f] = a;
}

// ---------------------------------------------------------------------------
// Kernel B: one thread per pixel.
//
// zbuf is sorted ascending -> zinv (masked) is decreasing over non-bg slots,
// so zmax belongs to the FIRST non-bg slot k0, and survivors (arg > -60) are
// a near-prefix: almost always just {k0}, sometimes {k0,k1}, >=3 is rare
// (~0.2% of lanes). Select k0 and k1 BRANCHLESSLY (cndmask chains), issue
// both slots' bary+attrs loads unconditionally and together -> ONE memory
// round-trip in the gather phase instead of 3-5 serialized branch blocks.
// A rare tail block handles >=3 survivors exactly.
// ---------------------------------------------------------------------------
__global__ __launch_bounds__(256) void shade_kernel(
    const int*   __restrict__ pix_to_face,
    const float* __restrict__ bary,
    const float* __restrict__ dists,
    const float* __restrict__ zbuf,
    const H16*   __restrict__ attrs,
    float*       __restrict__ out,
    int P)
{
    int pix = blockIdx.x * blockDim.x + threadIdx.x;
    if (pix >= P) return;

    // Streaming loads: non-temporal (no reuse; keep L2 for attrs/bary lines).
    const i32x4* p2f4 = reinterpret_cast<const i32x4*>(pix_to_face + (size_t)pix * 8);
    i32x4 f0 = __builtin_nontemporal_load(p2f4 + 0);
    i32x4 f1 = __builtin_nontemporal_load(p2f4 + 1);
    int faceid[8] = {f0.x, f0.y, f0.z, f0.w, f1.x, f1.y, f1.z, f1.w};

    const f32x4* d4 = reinterpret_cast<const f32x4*>(dists + (size_t)pix * 8);
    f32x4 da = __builtin_nontemporal_load(d4 + 0);
    f32x4 db = __builtin_nontemporal_load(d4 + 1);
    float dd[8] = {da.x, da.y, da.z, da.w, db.x, db.y, db.z, db.w};

    const f32x4* z4 = reinterpret_cast<const f32x4*>(zbuf + (size_t)pix * 8);
    f32x4 za = __builtin_nontemporal_load(z4 + 0);
    f32x4 zb = __builtin_nontemporal_load(z4 + 1);
    float zz[8] = {za.x, za.y, za.z, za.w, zb.x, zb.y, zb.z, zb.w};

    const float inv_sigma = 1.0f / SIGMA_F;
    const float inv_range = 1.0f / (ZFAR_F - ZNEAR_F);
    const float inv_gamma = 1.0f / GAMMA_F;

    // ---- Pass 1: per-slot prob/zinv, zmax, alpha (no gathers needed) ----
    float prob[8], zinv[8];
    float zmax = EPS_F;
    float one_minus_prod = 1.0f;

    #pragma unroll
    for (int k = 0; k < 8; ++k) {
        bool m = faceid[k] >= 0;
        float pm = 1.0f / (1.0f + __expf(dd[k] * inv_sigma));
        pm = m ? pm : 0.0f;
        prob[k] = pm;
        one_minus_prod *= (1.0f - pm);
        float zi = (ZFAR_F - zz[k]) * inv_range;
        zi = m ? zi : 0.0f;
        zinv[k] = zi;
        zmax = fmaxf(zmax, zi);
    }
    float alpha = 1.0f - one_minus_prod;

    // ---- Branchless select: k0 = first non-bg slot (owns zmax) ----
    int   k0 = 8, fsel = 0;
    float zsel = 0.0f, psel = 0.0f;
    #pragma unroll
    for (int k = 7; k >= 0; --k) {
        bool m = faceid[k] >= 0;
        k0   = m ? k          : k0;
        fsel = m ? faceid[k]  : fsel;
        zsel = m ? zinv[k]    : zsel;
        psel = m ? prob[k]    : psel;   // 0 if all-bg (k0 stays 8, psel 0)
    }

    // ---- Survivor mask for the remaining slots ----
    bool ext[8];
    #pragma unroll
    for (int k = 0; k < 8; ++k)
        ext[k] = (faceid[k] >= 0) && ((zinv[k] - zmax) * inv_gamma > CULL_ARG) && (k != k0);

    // ---- Branchless select: k1 = first extra survivor ----
    int   k1 = 8, f1sel = 0;
    float z1 = 0.0f, p1 = 0.0f;
    #pragma unroll
    for (int k = 7; k >= 0; --k) {
        bool e = ext[k];
        k1    = e ? k         : k1;
        f1sel = e ? faceid[k] : f1sel;
        z1    = e ? zinv[k]   : z1;
        p1    = e ? prob[k]   : p1;
    }
    bool has1 = (k1 < 8);

    // ---- Issue ALL common-path gathers together; one round-trip ----
    int ko0 = (k0 < 8) ? k0 : 0;
    int ko1 = has1 ? k1 : ko0;
    const float* bp = bary + (size_t)pix * 24;
    float a0 = bp[ko0 * 3 + 0], a1 = bp[ko0 * 3 + 1], a2 = bp[ko0 * 3 + 2];
    float c0 = bp[ko1 * 3 + 0], c1 = bp[ko1 * 3 + 1], c2 = bp[ko1 * 3 + 2];
    H16 g0 = attrs[fsel];
    H16 g1 = attrs[f1sel];

    float w0 = psel * __expf((zsel - zmax) * inv_gamma);     // ~= psel (zsel==zmax)
    float w1 = p1   * __expf((z1   - zmax) * inv_gamma);
    w1 = has1 ? w1 : 0.0f;

    float px0 = a0 * __half2float(g0.h[0]) + a1 * __half2float(g0.h[3]) + a2 * __half2float(g0.h[6]);
    float py0 = a0 * __half2float(g0.h[1]) + a1 * __half2float(g0.h[4]) + a2 * __half2float(g0.h[7]);
    float pz0 = a0 * __half2float(g0.h[2]) + a1 * __half2float(g0.h[5]) + a2 * __half2float(g0.h[8]);
    float px1 = c0 * __half2float(g1.h[0]) + c1 * __half2float(g1.h[3]) + c2 * __half2float(g1.h[6]);
    float py1 = c0 * __half2float(g1.h[1]) + c1 * __half2float(g1.h[4]) + c2 * __half2float(g1.h[7]);
    float pz1 = c0 * __half2float(g1.h[2]) + c1 * __half2float(g1.h[5]) + c2 * __half2float(g1.h[8]);

    float wsum = w0 + w1;
    float cr = w0 * px0 + w1 * px1;
    float cg = w0 * py0 + w1 * py1;
    float cb = w0 * pz0 + w1 * pz1;

    // ---- Rare tail: >=3 survivors (wave-level ~13%, few active lanes) ----
    bool more = false;
    #pragma unroll
    for (int k = 0; k < 8; ++k) more |= (ext[k] && k != k1);
    if (__any(more)) {
        #pragma unroll
        for (int k = 0; k < 8; ++k) {
            if (ext[k] && k != k1) {
                float b0 = bp[k * 3 + 0], b1 = bp[k * 3 + 1], b2 = bp[k * 3 + 2];
                H16 g = attrs[faceid[k]];
                float w = prob[k] * __expf((zinv[k] - zmax) * inv_gamma);
                float px = b0 * __half2float(g.h[0]) + b1 * __half2float(g.h[3]) + b2 * __half2float(g.h[6]);
                float py = b0 * __half2float(g.h[1]) + b1 * __half2float(g.h[4]) + b2 * __half2float(g.h[7]);
                float pz = b0 * __half2float(g.h[2]) + b1 * __half2float(g.h[5]) + b2 * __half2float(g.h[8]);
                wsum += w;
                cr += w * px;
                cg += w * py;
                cb += w * pz;
            }
        }
    }

    float delta = fmaxf(__expf((EPS_F - zmax) * inv_gamma), EPS_F);
    float inv_denom = 1.0f / (wsum + delta);

    f32x4 o;
    o.x = (cr + delta) * inv_denom;   // BG_COLOR = (1,1,1)
    o.y = (cg + delta) * inv_denom;
    o.z = (cb + delta) * inv_denom;
    o.w = alpha;
    __builtin_nontemporal_store(o, reinterpret_cast<f32x4*>(out) + pix);
}

// ---------------------------------------------------------------------------
// Fallback (no workspace): same structure, direct faces+vnorm double gather.
// ---------------------------------------------------------------------------
__global__ __launch_bounds__(256) void normal_shader_fused(
    const int*   __restrict__ pix_to_face,
    const float* __restrict__ bary,
    const float* __restrict__ dists,
    const float* __restrict__ zbuf,
    const int*   __restrict__ faces,
    const float* __restrict__ vnorm,
    float*       __restrict__ out,
    int P)
{
    int pix = blockIdx.x * blockDim.x + threadIdx.x;
    if (pix >= P) return;

    const i32x4* p2f4 = reinterpret_cast<const i32x4*>(pix_to_face + (size_t)pix * 8);
    i32x4 f0 = p2f4[0], f1 = p2f4[1];
    int faceid[8] = {f0.x, f0.y, f0.z, f0.w, f1.x, f1.y, f1.z, f1.w};

    const f32x4* d4 = reinterpret_cast<const f32x4*>(dists + (size_t)pix * 8);
    f32x4 da = d4[0], db = d4[1];
    float dd[8] = {da.x, da.y, da.z, da.w, db.x, db.y, db.z, db.w};

    const f32x4* z4 = reinterpret_cast<const f32x4*>(zbuf + (size_t)pix * 8);
    f32x4 za = z4[0], zb = z4[1];
    float zz[8] = {za.x, za.y, za.z, za.w, zb.x, zb.y, zb.z, zb.w};

    const float inv_sigma = 1.0f / SIGMA_F;
    const float inv_range = 1.0f / (ZFAR_F - ZNEAR_F);
    const float inv_gamma = 1.0f / GAMMA_F;

    float prob[8], zinv[8];
    float zmax = EPS_F, one_minus_prod = 1.0f;

    #pragma unroll
    for (int k = 0; k < 8; ++k) {
        bool m = faceid[k] >= 0;
        float pm = 1.0f / (1.0f + __expf(dd[k] * inv_sigma));
        pm = m ? pm : 0.0f;
        prob[k] = pm;
        one_minus_prod *= (1.0f - pm);
        float zi = (ZFAR_F - zz[k]) * inv_range;
        zinv[k] = m ? zi : 0.0f;
        zmax = fmaxf(zmax, zinv[k]);
    }
    float alpha = 1.0f - one_minus_prod;

    int k0 = 8, fsel = 0; float zsel = 0.0f, psel = 0.0f;
    #pragma unroll
    for (int k = 7; k >= 0; --k) {
        bool m = faceid[k] >= 0;
        k0 = m ? k : k0; fsel = m ? faceid[k] : fsel;
        zsel = m ? zinv[k] : zsel; psel = m ? prob[k] : psel;
    }

    bool ext[8];
    #pragma unroll
    for (int k = 0; k < 8; ++k)
        ext[k] = (faceid[k] >= 0) && ((zinv[k] - zmax) * inv_gamma > CULL_ARG) && (k != k0);

    int k1 = 8, f1sel = 0; float z1 = 0.0f, p1 = 0.0f;
    #pragma unroll
    for (int k = 7; k >= 0; --k) {
        bool e = ext[k];
        k1 = e ? k : k1; f1sel = e ? faceid[k] : f1sel;
        z1 = e ? zinv[k] : z1; p1 = e ? prob[k] : p1;
    }
    bool has1 = (k1 < 8);

    int ko0 = (k0 < 8) ? k0 : 0;
    int ko1 = has1 ? k1 : ko0;
    const float* bp = bary + (size_t)pix * 24;
    float a0 = bp[ko0 * 3 + 0], a1 = bp[ko0 * 3 + 1], a2 = bp[ko0 * 3 + 2];
    float c0 = bp[ko1 * 3 + 0], c1 = bp[ko1 * 3 + 1], c2 = bp[ko1 * 3 + 2];

    int v00 = faces[(size_t)fsel * 3 + 0], v01 = faces[(size_t)fsel * 3 + 1], v02 = faces[(size_t)fsel * 3 + 2];
    int v10 = faces[(size_t)f1sel * 3 + 0], v11 = faces[(size_t)f1sel * 3 + 1], v12 = faces[(size_t)f1sel * 3 + 2];

    float w0 = psel * __expf((zsel - zmax) * inv_gamma);
    float w1 = p1 * __expf((z1 - zmax) * inv_gamma);
    w1 = has1 ? w1 : 0.0f;

    const float* n00 = vnorm + (size_t)v00 * 3;
    const float* n01 = vnorm + (size_t)v01 * 3;
    const float* n02 = vnorm + (size_t)v02 * 3;
    const float* n10 = vnorm + (size_t)v10 * 3;
    const float* n11 = vnorm + (size_t)v11 * 3;
    const float* n12 = vnorm + (size_t)v12 * 3;

    float px0 = a0 * n00[0] + a1 * n01[0] + a2 * n02[0];
    float py0 = a0 * n00[1] + a1 * n01[1] + a2 * n02[1];
    float pz0 = a0 * n00[2] + a1 * n01[2] + a2 * n02[2];
    float px1 = c0 * n10[0] + c1 * n11[0] + c2 * n12[0];
    float py1 = c0 * n10[1] + c1 * n11[1] + c2 * n12[1];
    float pz1 = c0 * n10[2] + c1 * n11[2] + c2 * n12[2];

    float wsum = w0 + w1;
    float cr = w0 * px0 + w1 * px1;
    float cg = w0 * py0 + w1 * py1;
    float cb = w0 * pz0 + w1 * pz1;

    bool more = false;
    #pragma unroll
    for (int k = 0; k < 8; ++k) more |= (ext[k] && k != k1);
    if (__any(more)) {
        #pragma unroll
        for (int k = 0; k < 8; ++k) {
            if (ext[k] && k != k1) {
                int fi = faceid[k];
                int u0 = faces[(size_t)fi * 3 + 0];
                int u1 = faces[(size_t)fi * 3 + 1];
                int u2 = faces[(size_t)fi * 3 + 2];
                float b0 = bp[k * 3 + 0], b1 = bp[k * 3 + 1], b2 = bp[k * 3 + 2];
                const float* m0 = vnorm + (size_t)u0 * 3;
                const float* m1 = vnorm + (size_t)u1 * 3;
                const float* m2 = vnorm + (size_t)u2 * 3;
                float w = prob[k] * __expf((zinv[k] - zmax) * inv_gamma);
                wsum += w;
                cr += w * (b0 * m0[0] + b1 * m1[0] + b2 * m2[0]);
                cg += w * (b0 * m0[1] + b1 * m1[1] + b2 * m2[1]);
                cb += w * (b0 * m0[2] + b1 * m1[2] + b2 * m2[2]);
            }
        }
    }

    float delta = fmaxf(__expf((EPS_F - zmax) * inv_gamma), EPS_F);
    float inv_denom = 1.0f / (wsum + delta);
    f32x4 o;
    o.x = (cr + delta) * inv_denom;
    o.y = (cg + delta) * inv_denom;
    o.z = (cb + delta) * inv_denom;
    o.w = alpha;
    reinterpret_cast<f32x4*>(out)[pix] = o;
}

extern "C" void kernel_launch(void* const* d_in, const int* in_sizes, int n_in,
                              void* d_out, int out_size, void* d_ws, size_t ws_size,
                              hipStream_t stream) {
    const int*   pix_to_face = (const int*)  d_in[0];
    const float* bary        = (const float*)d_in[1];
    const float* dists       = (const float*)d_in[2];
    const float* zbuf        = (const float*)d_in[3];
    const int*   faces       = (const int*)  d_in[4];
    const float* vnorm       = (const float*)d_in[5];
    float*       out         = (float*)d_out;

    int P = out_size / 4;       // N*H*W pixels
    int F = in_sizes[4] / 3;    // number of faces
    int block = 256;
    int gridP = (P + block - 1) / block;

    size_t attrs_bytes = (size_t)F * sizeof(H16);
    if (ws_size >= attrs_bytes) {
        H16* attrs = (H16*)d_ws;
        int gridF = (F + block - 1) / block;
        build_face_attrs<<<gridF, block, 0, stream>>>(faces, vnorm, attrs, F);
        shade_kernel<<<gridP, block, 0, stream>>>(
            pix_to_face, bary, dists, zbuf, attrs, out, P);
    } else {
        normal_shader_fused<<<gridP, block, 0, stream>>>(
            pix_to_face, bary, dists, zbuf, faces, vnorm, out, P);
    }
}